// Round 8
// baseline (856.327 us; speedup 1.0000x reference)
//
#include <hip/hip_runtime.h>

#define N_NODES 100000
#define N_EDGES 1600000
#define F 128

#define SCAN_B 1024
#define SCAN_NB ((N_NODES + SCAN_B - 1) / SCAN_B)   // 98

typedef short bf16x8 __attribute__((ext_vector_type(8)));
typedef float f32x4  __attribute__((ext_vector_type(4)));

union ABFrag {
    bf16x8 v;
    unsigned short u[8];
    uint4  q;
};

__device__ __forceinline__ unsigned short f2bf(float f) {
    unsigned int u = __float_as_uint(f);
    u += 0x7fffu + ((u >> 16) & 1u);   // RNE
    return (unsigned short)(u >> 16);
}
__device__ __forceinline__ float bflo(unsigned int u) {   // low short -> f32
    return __uint_as_float(u << 16);
}
__device__ __forceinline__ float bfhi(unsigned int u) {   // high short -> f32
    return __uint_as_float(u & 0xFFFF0000u);
}

// ---------------- CSR build ----------------

__global__ void edge_histogram(const int* __restrict__ erow, int* __restrict__ counts) {
    const int e = blockIdx.x * blockDim.x + threadIdx.x;
    atomicAdd(&counts[erow[e]], 1);
}

__global__ void scan_block_sums(const int* __restrict__ counts, int* __restrict__ bsums) {
    __shared__ int s[SCAN_B];
    const int t = threadIdx.x;
    const int idx = blockIdx.x * SCAN_B + t;
    int v = (idx < N_NODES) ? counts[idx] : 0;
    s[t] = v;
    __syncthreads();
    for (int off = SCAN_B / 2; off > 0; off >>= 1) {
        if (t < off) s[t] += s[t + off];
        __syncthreads();
    }
    if (t == 0) bsums[blockIdx.x] = s[0];
}

__global__ void scan_bsums(const int* __restrict__ bsums, int* __restrict__ boffs) {
    __shared__ int s[128];
    const int t = threadIdx.x;
    int v = (t < SCAN_NB) ? bsums[t] : 0;
    s[t] = v;
    __syncthreads();
    for (int off = 1; off < 128; off <<= 1) {
        int u = (t >= off) ? s[t - off] : 0;
        __syncthreads();
        s[t] += u;
        __syncthreads();
    }
    if (t < SCAN_NB) boffs[t] = s[t] - v;
}

__global__ void scan_final(const int* __restrict__ counts, const int* __restrict__ boffs,
                           int* __restrict__ row_ptr) {
    __shared__ int s[SCAN_B];
    const int t = threadIdx.x;
    const int idx = blockIdx.x * SCAN_B + t;
    int v = (idx < N_NODES) ? counts[idx] : 0;
    s[t] = v;
    __syncthreads();
    for (int off = 1; off < SCAN_B; off <<= 1) {
        int u = (t >= off) ? s[t - off] : 0;
        __syncthreads();
        s[t] += u;
        __syncthreads();
    }
    if (idx < N_NODES) row_ptr[idx] = boffs[blockIdx.x] + s[t] - v;
    if (idx == 0) row_ptr[N_NODES] = N_EDGES;
}

// One 4 B packed store per edge: (col << 15) | bf16(weight) [weight sign is 0].
__global__ void csr_fill(const int* __restrict__ erow, const int* __restrict__ ecol,
                         const float* __restrict__ ewgt,
                         const int* __restrict__ row_ptr, int* __restrict__ cursor,
                         unsigned int* __restrict__ pairs) {
    const int e = blockIdx.x * blockDim.x + threadIdx.x;
    const int dst = erow[e];
    const int pos = atomicAdd(&cursor[dst], 1);
    pairs[row_ptr[dst] + pos] = ((unsigned int)ecol[e] << 15) | (unsigned int)f2bf(ewgt[e]);
}

// ---------------- W^T -> bf16 (once per weight) ----------------
__global__ void transpose_w_bf16(const float* __restrict__ W, unsigned short* __restrict__ Wt) {
    const int i = blockIdx.x * 256 + threadIdx.x;   // 0..16383
    const int n = i >> 7;
    const int k = i & 127;
    Wt[i] = f2bf(W[k * F + n]);                     // Wt[n][k] = W[k][n]
}

// ---------------- MFMA bf16 GEMM (R4 structure, proven) ----------------
__global__ __launch_bounds__(256) void gemm_mfma(
    const float* __restrict__ Xf,            // fp32 input (layer 1) or null
    const unsigned short* __restrict__ Xb,   // bf16 input (layers 2/3) or null
    const unsigned short* __restrict__ Wt,   // bf16 W^T [128][128]
    unsigned short* __restrict__ Y,          // bf16 out [N][128]
    int use_f32_in)                          // 1: Xf no relu; 0: Xb with relu
{
    __shared__ unsigned short Wl[4 * 8 * 64 * 8];   // 32 KB, frag order

    const int tid  = threadIdx.x;
    const int wave = tid >> 6;
    const int lane = tid & 63;

    for (int s = tid; s < 2048; s += 256) {
        const int ln  = s & 63;
        const int ntk = s >> 6;           // kt*8 + nt
        const int nt  = ntk & 7;
        const int kt  = ntk >> 3;
        const int n   = nt * 16 + (ln & 15);
        const int k   = kt * 32 + (ln >> 4) * 8;
        *(uint4*)(&Wl[s * 8]) = *(const uint4*)(Wt + n * F + k);
    }
    __syncthreads();

    const int m     = blockIdx.x * 64 + wave * 16 + (lane & 15);
    const bool mval = (m < N_NODES);
    const int kq    = (lane >> 4) * 8;

    f32x4 acc[8] = {};

#pragma unroll
    for (int kt = 0; kt < 4; ++kt) {
        ABFrag a;
        if (mval) {
            if (use_f32_in) {
                const float* p = Xf + (size_t)m * F + kt * 32 + kq;
                const float4 u0 = *(const float4*)p;
                const float4 u1 = *(const float4*)(p + 4);
                a.u[0] = f2bf(u0.x); a.u[1] = f2bf(u0.y);
                a.u[2] = f2bf(u0.z); a.u[3] = f2bf(u0.w);
                a.u[4] = f2bf(u1.x); a.u[5] = f2bf(u1.y);
                a.u[6] = f2bf(u1.z); a.u[7] = f2bf(u1.w);
            } else {
                a.q = *(const uint4*)(Xb + (size_t)m * F + kt * 32 + kq);
#pragma unroll
                for (int j = 0; j < 8; ++j)
                    if (a.u[j] & 0x8000u) a.u[j] = 0;   // relu on bf16 bits
            }
        } else {
            a.q = make_uint4(0, 0, 0, 0);
        }
#pragma unroll
        for (int nt = 0; nt < 8; ++nt) {
            ABFrag b;
            b.q = *(const uint4*)(&Wl[((kt * 8 + nt) * 64 + lane) * 8]);
            acc[nt] = __builtin_amdgcn_mfma_f32_16x16x32_bf16(a.v, b.v, acc[nt], 0, 0, 0);
        }
    }

    const int rbase = blockIdx.x * 64 + wave * 16 + (lane >> 4) * 4;
    const int cbase = lane & 15;
#pragma unroll
    for (int r = 0; r < 4; ++r) {
        const int row = rbase + r;
        if (row < N_NODES) {
#pragma unroll
            for (int nt = 0; nt < 8; ++nt) {
                Y[(size_t)row * F + nt * 16 + cbase] = f2bf(acc[nt][r]);
            }
        }
    }
}

// ---------------- XCD-sliced CSR SpMM ----------------
// Feature dim split into 8 slices of 16 cols; slice = blockIdx & 7 pins each
// slice to one XCD (round-robin dispatch) -> hot X-slice (100000 x 32 B =
// 3.2 MB) stays L2-resident. Within a quarter-wave (16 lanes): 2 lanes per
// edge (uint4 = 8 bf16 each), 8 edge-slots in flight; butterfly-shuffle
// reduction over slots. Pairs are re-streamed per slice -> non-temporal.
// Block 256 = 16 rows; grid = 8 * (N_NODES/16).
__global__ __launch_bounds__(256) void spmm_sliced(
    const unsigned short* __restrict__ Xb,
    const int* __restrict__ row_ptr,
    const unsigned int* __restrict__ pairs,
    unsigned short* __restrict__ Ob,
    float* __restrict__ Of,
    int final_mode) {
    const int tid    = threadIdx.x;
    const int slice  = blockIdx.x & 7;
    const int chunk  = blockIdx.x >> 3;
    const int row    = chunk * 16 + (tid >> 4);
    const int l16    = tid & 15;
    const int epos   = l16 >> 1;          // edge slot 0..7
    const int par    = l16 & 1;           // col half within slice
    const int colOff = slice * 16 + par * 8;

    const int beg = row_ptr[row];
    const int end = row_ptr[row + 1];

    float a[8] = {};
    int i = beg + epos;
    for (; i + 8 < end; i += 16) {
        const unsigned int p0 = __builtin_nontemporal_load(&pairs[i]);
        const unsigned int p1 = __builtin_nontemporal_load(&pairs[i + 8]);
        const uint4 v0 = *(const uint4*)(Xb + (size_t)(p0 >> 15) * F + colOff);
        const uint4 v1 = *(const uint4*)(Xb + (size_t)(p1 >> 15) * F + colOff);
        const float w0 = bflo(p0 & 0x7FFFu);
        const float w1 = bflo(p1 & 0x7FFFu);
        a[0] += w0 * bflo(v0.x); a[1] += w0 * bfhi(v0.x);
        a[2] += w0 * bflo(v0.y); a[3] += w0 * bfhi(v0.y);
        a[4] += w0 * bflo(v0.z); a[5] += w0 * bfhi(v0.z);
        a[6] += w0 * bflo(v0.w); a[7] += w0 * bfhi(v0.w);
        a[0] += w1 * bflo(v1.x); a[1] += w1 * bfhi(v1.x);
        a[2] += w1 * bflo(v1.y); a[3] += w1 * bfhi(v1.y);
        a[4] += w1 * bflo(v1.z); a[5] += w1 * bfhi(v1.z);
        a[6] += w1 * bflo(v1.w); a[7] += w1 * bfhi(v1.w);
    }
    if (i < end) {
        const unsigned int p0 = __builtin_nontemporal_load(&pairs[i]);
        const uint4 v0 = *(const uint4*)(Xb + (size_t)(p0 >> 15) * F + colOff);
        const float w0 = bflo(p0 & 0x7FFFu);
        a[0] += w0 * bflo(v0.x); a[1] += w0 * bfhi(v0.x);
        a[2] += w0 * bflo(v0.y); a[3] += w0 * bfhi(v0.y);
        a[4] += w0 * bflo(v0.z); a[5] += w0 * bfhi(v0.z);
        a[6] += w0 * bflo(v0.w); a[7] += w0 * bfhi(v0.w);
    }

    // Reduce over the 8 edge slots (lanes with same parity, strides 2/4/8).
#pragma unroll
    for (int s = 2; s <= 8; s <<= 1) {
#pragma unroll
        for (int j = 0; j < 8; ++j) a[j] += __shfl_xor(a[j], s);
    }

    if (epos == 0) {
        if (final_mode) {
            float* p = Of + (size_t)row * F + colOff;
            float4 o0 = {fmaxf(a[0], 0.f), fmaxf(a[1], 0.f), fmaxf(a[2], 0.f), fmaxf(a[3], 0.f)};
            float4 o1 = {fmaxf(a[4], 0.f), fmaxf(a[5], 0.f), fmaxf(a[6], 0.f), fmaxf(a[7], 0.f)};
            *(float4*)p = o0;
            *(float4*)(p + 4) = o1;
        } else {
            uint4 o;
            o.x = (unsigned int)f2bf(a[0]) | ((unsigned int)f2bf(a[1]) << 16);
            o.y = (unsigned int)f2bf(a[2]) | ((unsigned int)f2bf(a[3]) << 16);
            o.z = (unsigned int)f2bf(a[4]) | ((unsigned int)f2bf(a[5]) << 16);
            o.w = (unsigned int)f2bf(a[6]) | ((unsigned int)f2bf(a[7]) << 16);
            *(uint4*)(Ob + (size_t)row * F + colOff) = o;
        }
    }
}

// ---------------- launch ----------------

extern "C" void kernel_launch(void* const* d_in, const int* in_sizes, int n_in,
                              void* d_out, int out_size, void* d_ws, size_t ws_size,
                              hipStream_t stream) {
    const float* x    = (const float*)d_in[0];
    const int*   erow = (const int*)d_in[1];
    const int*   ecol = (const int*)d_in[2];
    const float* ew   = (const float*)d_in[3];
    const float* w1   = (const float*)d_in[4];
    const float* w2   = (const float*)d_in[5];
    const float* w3   = (const float*)d_in[6];
    float* out = (float*)d_out;

    char* ws = (char*)d_ws;
    size_t off = 0;
    auto alloc = [&](size_t bytes) -> char* {
        char* p = ws + off;
        off += (bytes + 255) & ~(size_t)255;
        return p;
    };
    unsigned short* bufA = (unsigned short*)alloc((size_t)N_NODES * F * 2); // 25.6 MB
    unsigned short* bufB = (unsigned short*)alloc((size_t)N_NODES * F * 2); // 25.6 MB
    unsigned int* pairs  = (unsigned int*)alloc((size_t)N_EDGES * 4);       // 6.4 MB
    int* counts  = (int*)alloc((size_t)N_NODES * sizeof(int) * 2);          // counts + cursor, adjacent
    int* cursor  = counts + N_NODES;
    int* row_ptr = (int*)alloc(((size_t)N_NODES + 1) * sizeof(int));
    int* bsums   = (int*)alloc((size_t)SCAN_NB * sizeof(int));
    int* boffs   = (int*)alloc((size_t)SCAN_NB * sizeof(int));
    unsigned short* wt1 = (unsigned short*)alloc((size_t)F * F * 2);
    unsigned short* wt2 = (unsigned short*)alloc((size_t)F * F * 2);
    unsigned short* wt3 = (unsigned short*)alloc((size_t)F * F * 2);

    // --- CSR build (once; reused by all 3 layers) ---
    hipMemsetAsync(counts, 0, (size_t)N_NODES * sizeof(int) * 2, stream);  // counts + cursor
    edge_histogram<<<N_EDGES / 256, 256, 0, stream>>>(erow, counts);
    scan_block_sums<<<SCAN_NB, SCAN_B, 0, stream>>>(counts, bsums);
    scan_bsums<<<1, 128, 0, stream>>>(bsums, boffs);
    scan_final<<<SCAN_NB, SCAN_B, 0, stream>>>(counts, boffs, row_ptr);
    csr_fill<<<N_EDGES / 256, 256, 0, stream>>>(erow, ecol, ew, row_ptr, cursor, pairs);

    // --- Weight transposes to bf16 ---
    transpose_w_bf16<<<64, 256, 0, stream>>>(w1, wt1);
    transpose_w_bf16<<<64, 256, 0, stream>>>(w2, wt2);
    transpose_w_bf16<<<64, 256, 0, stream>>>(w3, wt3);

    const int ggrid = (N_NODES + 63) / 64;     // 1563
    const int sgrid = 8 * (N_NODES / 16);      // 50000 exact

    // Layer 1
    gemm_mfma<<<ggrid, 256, 0, stream>>>(x, nullptr, wt1, bufA, 1);
    spmm_sliced<<<sgrid, 256, 0, stream>>>(bufA, row_ptr, pairs, bufB, nullptr, 0);
    // Layer 2
    gemm_mfma<<<ggrid, 256, 0, stream>>>(nullptr, bufB, wt2, bufA, 0);
    spmm_sliced<<<sgrid, 256, 0, stream>>>(bufA, row_ptr, pairs, bufB, nullptr, 0);
    // Layer 3
    gemm_mfma<<<ggrid, 256, 0, stream>>>(nullptr, bufB, wt3, bufA, 0);
    spmm_sliced<<<sgrid, 256, 0, stream>>>(bufA, row_ptr, pairs, nullptr, out, 1);
}

// Round 9
// 648.534 us; speedup vs baseline: 1.3204x; 1.3204x over previous
//
#include <hip/hip_runtime.h>

#define N_NODES 100000
#define N_EDGES 1600000
#define F 128
#define XCD_RANGE 12500   // N_NODES / 8

#define SCAN_B 1024
#define SCAN_NB ((N_NODES + SCAN_B - 1) / SCAN_B)   // 98

typedef short bf16x8 __attribute__((ext_vector_type(8)));
typedef float f32x4  __attribute__((ext_vector_type(4)));

union ABFrag {
    bf16x8 v;
    unsigned short u[8];
    uint4  q;
};

__device__ __forceinline__ unsigned short f2bf(float f) {
    unsigned int u = __float_as_uint(f);
    u += 0x7fffu + ((u >> 16) & 1u);   // RNE
    return (unsigned short)(u >> 16);
}
__device__ __forceinline__ float bflo(unsigned int u) {   // low short -> f32
    return __uint_as_float(u << 16);
}
__device__ __forceinline__ float bfhi(unsigned int u) {   // high short -> f32
    return __uint_as_float(u & 0xFFFF0000u);
}

// ---------------- CSR build ----------------

__global__ void edge_histogram(const int* __restrict__ erow, int* __restrict__ counts) {
    const int e = blockIdx.x * blockDim.x + threadIdx.x;
    atomicAdd(&counts[erow[e]], 1);
}

__global__ void scan_block_sums(const int* __restrict__ counts, int* __restrict__ bsums) {
    __shared__ int s[SCAN_B];
    const int t = threadIdx.x;
    const int idx = blockIdx.x * SCAN_B + t;
    int v = (idx < N_NODES) ? counts[idx] : 0;
    s[t] = v;
    __syncthreads();
    for (int off = SCAN_B / 2; off > 0; off >>= 1) {
        if (t < off) s[t] += s[t + off];
        __syncthreads();
    }
    if (t == 0) bsums[blockIdx.x] = s[0];
}

__global__ void scan_bsums(const int* __restrict__ bsums, int* __restrict__ boffs) {
    __shared__ int s[128];
    const int t = threadIdx.x;
    int v = (t < SCAN_NB) ? bsums[t] : 0;
    s[t] = v;
    __syncthreads();
    for (int off = 1; off < 128; off <<= 1) {
        int u = (t >= off) ? s[t - off] : 0;
        __syncthreads();
        s[t] += u;
        __syncthreads();
    }
    if (t < SCAN_NB) boffs[t] = s[t] - v;
}

__global__ void scan_final(const int* __restrict__ counts, const int* __restrict__ boffs,
                           int* __restrict__ row_ptr) {
    __shared__ int s[SCAN_B];
    const int t = threadIdx.x;
    const int idx = blockIdx.x * SCAN_B + t;
    int v = (idx < N_NODES) ? counts[idx] : 0;
    s[t] = v;
    __syncthreads();
    for (int off = 1; off < SCAN_B; off <<= 1) {
        int u = (t >= off) ? s[t - off] : 0;
        __syncthreads();
        s[t] += u;
        __syncthreads();
    }
    if (idx < N_NODES) row_ptr[idx] = boffs[blockIdx.x] + s[t] - v;
    if (idx == 0) row_ptr[N_NODES] = N_EDGES;
}

// XCD-partitioned scatter: block (blockIdx&7) accepts only dst in its 12500-row
// range; each XCD writes a disjoint contiguous CSR region -> lines merge in its
// own L2 instead of churning across 8 non-coherent L2s. Edge stream re-read 8x
// (streaming, cheap); scatter writes drop from E*64B line-churn to ~|pairs|.
__global__ __launch_bounds__(256) void csr_fill_xcd(
    const int* __restrict__ erow, const int* __restrict__ ecol,
    const float* __restrict__ ewgt,
    const int* __restrict__ row_ptr, int* __restrict__ cursor,
    unsigned int* __restrict__ pairs) {
    const int xcd = blockIdx.x & 7;
    const int e   = (blockIdx.x >> 3) * 256 + threadIdx.x;
    const int dst = erow[e];
    const int lo  = xcd * XCD_RANGE;
    const int col = ecol[e];
    const float w = ewgt[e];
    if (dst >= lo && dst < lo + XCD_RANGE) {
        const int pos = atomicAdd(&cursor[dst], 1);
        pairs[row_ptr[dst] + pos] = ((unsigned int)col << 15) | (unsigned int)f2bf(w);
    }
}

// ---------------- W^T -> bf16 (once per weight) ----------------
__global__ void transpose_w_bf16(const float* __restrict__ W, unsigned short* __restrict__ Wt) {
    const int i = blockIdx.x * 256 + threadIdx.x;   // 0..16383
    const int n = i >> 7;
    const int k = i & 127;
    Wt[i] = f2bf(W[k * F + n]);                     // Wt[n][k] = W[k][n]
}

// ---------------- MFMA bf16 GEMM, slice-major I/O ----------------
// Slice-major layout: X[s][node][16] shorts, s = col/16 (8 slices, each a
// contiguous 3.2 MB region). A-frag 8-col spans never cross a slice.
// Epilogue nt-tile (16 cols) == one slice -> slice-major write, no cross-XCD
// line sharing (64-row blocks own whole lines).
__global__ __launch_bounds__(256) void gemm_mfma(
    const float* __restrict__ Xf,            // fp32 row-major input (layer 1) or null
    const unsigned short* __restrict__ Xb,   // bf16 slice-major input (layers 2/3) or null
    const unsigned short* __restrict__ Wt,   // bf16 W^T [128][128]
    unsigned short* __restrict__ Y,          // bf16 slice-major out
    int use_f32_in)                          // 1: Xf no relu; 0: Xb with relu
{
    __shared__ unsigned short Wl[4 * 8 * 64 * 8];   // 32 KB, frag order

    const int tid  = threadIdx.x;
    const int wave = tid >> 6;
    const int lane = tid & 63;

    for (int s = tid; s < 2048; s += 256) {
        const int ln  = s & 63;
        const int ntk = s >> 6;           // kt*8 + nt
        const int nt  = ntk & 7;
        const int kt  = ntk >> 3;
        const int n   = nt * 16 + (ln & 15);
        const int k   = kt * 32 + (ln >> 4) * 8;
        *(uint4*)(&Wl[s * 8]) = *(const uint4*)(Wt + n * F + k);
    }
    __syncthreads();

    const int m     = blockIdx.x * 64 + wave * 16 + (lane & 15);
    const bool mval = (m < N_NODES);
    const int kq    = (lane >> 4) * 8;     // 0,8,16,24

    f32x4 acc[8] = {};

#pragma unroll
    for (int kt = 0; kt < 4; ++kt) {
        ABFrag a;
        if (mval) {
            if (use_f32_in) {
                const float* p = Xf + (size_t)m * F + kt * 32 + kq;
                const float4 u0 = *(const float4*)p;
                const float4 u1 = *(const float4*)(p + 4);
                a.u[0] = f2bf(u0.x); a.u[1] = f2bf(u0.y);
                a.u[2] = f2bf(u0.z); a.u[3] = f2bf(u0.w);
                a.u[4] = f2bf(u1.x); a.u[5] = f2bf(u1.y);
                a.u[6] = f2bf(u1.z); a.u[7] = f2bf(u1.w);
            } else {
                const int slice = kt * 2 + (kq >> 4);
                a.q = *(const uint4*)(Xb + ((size_t)slice * N_NODES + m) * 16 + (kq & 8));
#pragma unroll
                for (int j = 0; j < 8; ++j)
                    if (a.u[j] & 0x8000u) a.u[j] = 0;   // relu on bf16 bits
            }
        } else {
            a.q = make_uint4(0, 0, 0, 0);
        }
#pragma unroll
        for (int nt = 0; nt < 8; ++nt) {
            ABFrag b;
            b.q = *(const uint4*)(&Wl[((kt * 8 + nt) * 64 + lane) * 8]);
            acc[nt] = __builtin_amdgcn_mfma_f32_16x16x32_bf16(a.v, b.v, acc[nt], 0, 0, 0);
        }
    }

    const int rbase = blockIdx.x * 64 + wave * 16 + (lane >> 4) * 4;
    const int cbase = lane & 15;
#pragma unroll
    for (int r = 0; r < 4; ++r) {
        const int row = rbase + r;
        if (row < N_NODES) {
#pragma unroll
            for (int nt = 0; nt < 8; ++nt) {   // nt == slice
                Y[((size_t)nt * N_NODES + row) * 16 + cbase] = f2bf(acc[nt][r]);
            }
        }
    }
}

// ---------------- XCD-sliced CSR SpMM, slice-major gather ----------------
// slice = blockIdx & 7 pins each slice to one XCD; slice region is now a
// CONTIGUOUS 3.2 MB block -> truly L2-resident (R7's flaw: 32 B slices strided
// inside 256 B rows touched every line). 16 lanes per row: 8 edge slots x
// 2 col-halves (uint4 = 8 bf16); butterfly reduce over slots.
// Writes: slice-major bf16 (layers 1,2) or row-major fp32 (final; each slice
// owns one aligned 64 B line per row -> no cross-XCD write sharing).
__global__ __launch_bounds__(256) void spmm_sliced(
    const unsigned short* __restrict__ Xb,   // slice-major
    const int* __restrict__ row_ptr,
    const unsigned int* __restrict__ pairs,
    unsigned short* __restrict__ Ob,         // slice-major
    float* __restrict__ Of,                  // row-major fp32
    int final_mode) {
    const int tid   = threadIdx.x;
    const int slice = blockIdx.x & 7;
    const int chunk = blockIdx.x >> 3;
    const int row   = chunk * 16 + (tid >> 4);
    const int l16   = tid & 15;
    const int epos  = l16 >> 1;          // edge slot 0..7
    const int par   = l16 & 1;           // col half within slice

    const unsigned short* Xs = Xb + (size_t)slice * N_NODES * 16 + par * 8;

    const int beg = row_ptr[row];
    const int end = row_ptr[row + 1];

    float a[8] = {};
    int i = beg + epos;
    for (; i + 8 < end; i += 16) {
        const unsigned int p0 = __builtin_nontemporal_load(&pairs[i]);
        const unsigned int p1 = __builtin_nontemporal_load(&pairs[i + 8]);
        const uint4 v0 = *(const uint4*)(Xs + (size_t)(p0 >> 15) * 16);
        const uint4 v1 = *(const uint4*)(Xs + (size_t)(p1 >> 15) * 16);
        const float w0 = bflo(p0 & 0x7FFFu);
        const float w1 = bflo(p1 & 0x7FFFu);
        a[0] += w0 * bflo(v0.x); a[1] += w0 * bfhi(v0.x);
        a[2] += w0 * bflo(v0.y); a[3] += w0 * bfhi(v0.y);
        a[4] += w0 * bflo(v0.z); a[5] += w0 * bfhi(v0.z);
        a[6] += w0 * bflo(v0.w); a[7] += w0 * bfhi(v0.w);
        a[0] += w1 * bflo(v1.x); a[1] += w1 * bfhi(v1.x);
        a[2] += w1 * bflo(v1.y); a[3] += w1 * bfhi(v1.y);
        a[4] += w1 * bflo(v1.z); a[5] += w1 * bfhi(v1.z);
        a[6] += w1 * bflo(v1.w); a[7] += w1 * bfhi(v1.w);
    }
    if (i < end) {
        const unsigned int p0 = __builtin_nontemporal_load(&pairs[i]);
        const uint4 v0 = *(const uint4*)(Xs + (size_t)(p0 >> 15) * 16);
        const float w0 = bflo(p0 & 0x7FFFu);
        a[0] += w0 * bflo(v0.x); a[1] += w0 * bfhi(v0.x);
        a[2] += w0 * bflo(v0.y); a[3] += w0 * bfhi(v0.y);
        a[4] += w0 * bflo(v0.z); a[5] += w0 * bfhi(v0.z);
        a[6] += w0 * bflo(v0.w); a[7] += w0 * bfhi(v0.w);
    }

    // Reduce over the 8 edge slots (same parity; lane strides 2/4/8).
#pragma unroll
    for (int s = 2; s <= 8; s <<= 1) {
#pragma unroll
        for (int j = 0; j < 8; ++j) a[j] += __shfl_xor(a[j], s);
    }

    if (epos == 0) {
        if (final_mode) {
            float* p = Of + (size_t)row * F + slice * 16 + par * 8;
            float4 o0 = {fmaxf(a[0], 0.f), fmaxf(a[1], 0.f), fmaxf(a[2], 0.f), fmaxf(a[3], 0.f)};
            float4 o1 = {fmaxf(a[4], 0.f), fmaxf(a[5], 0.f), fmaxf(a[6], 0.f), fmaxf(a[7], 0.f)};
            *(float4*)p = o0;
            *(float4*)(p + 4) = o1;
        } else {
            uint4 o;
            o.x = (unsigned int)f2bf(a[0]) | ((unsigned int)f2bf(a[1]) << 16);
            o.y = (unsigned int)f2bf(a[2]) | ((unsigned int)f2bf(a[3]) << 16);
            o.z = (unsigned int)f2bf(a[4]) | ((unsigned int)f2bf(a[5]) << 16);
            o.w = (unsigned int)f2bf(a[6]) | ((unsigned int)f2bf(a[7]) << 16);
            *(uint4*)(Ob + ((size_t)slice * N_NODES + row) * 16 + par * 8) = o;
        }
    }
}

// ---------------- launch ----------------

extern "C" void kernel_launch(void* const* d_in, const int* in_sizes, int n_in,
                              void* d_out, int out_size, void* d_ws, size_t ws_size,
                              hipStream_t stream) {
    const float* x    = (const float*)d_in[0];
    const int*   erow = (const int*)d_in[1];
    const int*   ecol = (const int*)d_in[2];
    const float* ew   = (const float*)d_in[3];
    const float* w1   = (const float*)d_in[4];
    const float* w2   = (const float*)d_in[5];
    const float* w3   = (const float*)d_in[6];
    float* out = (float*)d_out;

    char* ws = (char*)d_ws;
    size_t off = 0;
    auto alloc = [&](size_t bytes) -> char* {
        char* p = ws + off;
        off += (bytes + 255) & ~(size_t)255;
        return p;
    };
    unsigned short* bufA = (unsigned short*)alloc((size_t)N_NODES * F * 2); // 25.6 MB slice-major
    unsigned short* bufB = (unsigned short*)alloc((size_t)N_NODES * F * 2); // 25.6 MB slice-major
    unsigned int* pairs  = (unsigned int*)alloc((size_t)N_EDGES * 4);       // 6.4 MB
    int* counts  = (int*)alloc((size_t)N_NODES * sizeof(int) * 2);          // counts + cursor
    int* cursor  = counts + N_NODES;
    int* row_ptr = (int*)alloc(((size_t)N_NODES + 1) * sizeof(int));
    int* bsums   = (int*)alloc((size_t)SCAN_NB * sizeof(int));
    int* boffs   = (int*)alloc((size_t)SCAN_NB * sizeof(int));
    unsigned short* wt1 = (unsigned short*)alloc((size_t)F * F * 2);
    unsigned short* wt2 = (unsigned short*)alloc((size_t)F * F * 2);
    unsigned short* wt3 = (unsigned short*)alloc((size_t)F * F * 2);

    // --- CSR build (once; reused by all 3 layers) ---
    hipMemsetAsync(counts, 0, (size_t)N_NODES * sizeof(int) * 2, stream);
    edge_histogram<<<N_EDGES / 256, 256, 0, stream>>>(erow, counts);
    scan_block_sums<<<SCAN_NB, SCAN_B, 0, stream>>>(counts, bsums);
    scan_bsums<<<1, 128, 0, stream>>>(bsums, boffs);
    scan_final<<<SCAN_NB, SCAN_B, 0, stream>>>(counts, boffs, row_ptr);
    csr_fill_xcd<<<8 * (N_EDGES / 256), 256, 0, stream>>>(erow, ecol, ew, row_ptr, cursor, pairs);

    // --- Weight transposes to bf16 ---
    transpose_w_bf16<<<64, 256, 0, stream>>>(w1, wt1);
    transpose_w_bf16<<<64, 256, 0, stream>>>(w2, wt2);
    transpose_w_bf16<<<64, 256, 0, stream>>>(w3, wt3);

    const int ggrid = (N_NODES + 63) / 64;     // 1563
    const int sgrid = 8 * (N_NODES / 16);      // 50000 exact

    // Layer 1
    gemm_mfma<<<ggrid, 256, 0, stream>>>(x, nullptr, wt1, bufA, 1);
    spmm_sliced<<<sgrid, 256, 0, stream>>>(bufA, row_ptr, pairs, bufB, nullptr, 0);
    // Layer 2
    gemm_mfma<<<ggrid, 256, 0, stream>>>(nullptr, bufB, wt2, bufA, 0);
    spmm_sliced<<<sgrid, 256, 0, stream>>>(bufA, row_ptr, pairs, bufB, nullptr, 0);
    // Layer 3
    gemm_mfma<<<ggrid, 256, 0, stream>>>(nullptr, bufB, wt3, bufA, 0);
    spmm_sliced<<<sgrid, 256, 0, stream>>>(bufA, row_ptr, pairs, nullptr, out, 1);
}

// Round 11
// 509.141 us; speedup vs baseline: 1.6819x; 1.2738x over previous
//
#include <hip/hip_runtime.h>

#define N_NODES 100000
#define N_EDGES 1600000
#define F 128
#define XCD_RANGE 12500   // N_NODES / 8

#define SCAN_B 1024
#define SCAN_NB ((N_NODES + SCAN_B - 1) / SCAN_B)   // 98

typedef short bf16x8 __attribute__((ext_vector_type(8)));
typedef float f32x4  __attribute__((ext_vector_type(4)));
typedef unsigned int u32x4 __attribute__((ext_vector_type(4)));   // clang vector: OK for NT builtins

union ABFrag {
    bf16x8 v;
    unsigned short u[8];
    u32x4  q;
};

__device__ __forceinline__ unsigned short f2bf(float f) {
    unsigned int u = __float_as_uint(f);
    u += 0x7fffu + ((u >> 16) & 1u);   // RNE
    return (unsigned short)(u >> 16);
}
__device__ __forceinline__ float bflo(unsigned int u) {   // low short -> f32
    return __uint_as_float(u << 16);
}
__device__ __forceinline__ float bfhi(unsigned int u) {   // high short -> f32
    return __uint_as_float(u & 0xFFFF0000u);
}

// ---------------- CSR build ----------------

// XCD-partitioned histogram: block (blockIdx&7) only counts dst in its
// 12500-row range -> each XCD's 50 KB counts region stays in its own L2.
__global__ __launch_bounds__(256) void edge_histogram_xcd(
    const int* __restrict__ erow, int* __restrict__ counts) {
    const int xcd = blockIdx.x & 7;
    const int e   = (blockIdx.x >> 3) * 256 + threadIdx.x;
    const int dst = erow[e];
    const int lo  = xcd * XCD_RANGE;
    if (dst >= lo && dst < lo + XCD_RANGE) {
        atomicAdd(&counts[dst], 1);
    }
}

__global__ void scan_block_sums(const int* __restrict__ counts, int* __restrict__ bsums) {
    __shared__ int s[SCAN_B];
    const int t = threadIdx.x;
    const int idx = blockIdx.x * SCAN_B + t;
    int v = (idx < N_NODES) ? counts[idx] : 0;
    s[t] = v;
    __syncthreads();
    for (int off = SCAN_B / 2; off > 0; off >>= 1) {
        if (t < off) s[t] += s[t + off];
        __syncthreads();
    }
    if (t == 0) bsums[blockIdx.x] = s[0];
}

__global__ void scan_bsums(const int* __restrict__ bsums, int* __restrict__ boffs) {
    __shared__ int s[128];
    const int t = threadIdx.x;
    int v = (t < SCAN_NB) ? bsums[t] : 0;
    s[t] = v;
    __syncthreads();
    for (int off = 1; off < 128; off <<= 1) {
        int u = (t >= off) ? s[t - off] : 0;
        __syncthreads();
        s[t] += u;
        __syncthreads();
    }
    if (t < SCAN_NB) boffs[t] = s[t] - v;
}

__global__ void scan_final(const int* __restrict__ counts, const int* __restrict__ boffs,
                           int* __restrict__ row_ptr) {
    __shared__ int s[SCAN_B];
    const int t = threadIdx.x;
    const int idx = blockIdx.x * SCAN_B + t;
    int v = (idx < N_NODES) ? counts[idx] : 0;
    s[t] = v;
    __syncthreads();
    for (int off = 1; off < SCAN_B; off <<= 1) {
        int u = (t >= off) ? s[t - off] : 0;
        __syncthreads();
        s[t] += u;
        __syncthreads();
    }
    if (idx < N_NODES) row_ptr[idx] = boffs[blockIdx.x] + s[t] - v;
    if (idx == 0) row_ptr[N_NODES] = N_EDGES;
}

// XCD-partitioned scatter (R8 win). ecol/ewgt loads inside the predicate:
// only erow is re-streamed 8x.
__global__ __launch_bounds__(256) void csr_fill_xcd(
    const int* __restrict__ erow, const int* __restrict__ ecol,
    const float* __restrict__ ewgt,
    const int* __restrict__ row_ptr, int* __restrict__ cursor,
    unsigned int* __restrict__ pairs) {
    const int xcd = blockIdx.x & 7;
    const int e   = (blockIdx.x >> 3) * 256 + threadIdx.x;
    const int dst = erow[e];
    const int lo  = xcd * XCD_RANGE;
    if (dst >= lo && dst < lo + XCD_RANGE) {
        const int col = ecol[e];
        const float w = ewgt[e];
        const int pos = atomicAdd(&cursor[dst], 1);
        pairs[row_ptr[dst] + pos] = ((unsigned int)col << 15) | (unsigned int)f2bf(w);
    }
}

// ---------------- all 3 weights -> bf16 W^T, one launch ----------------
__global__ void transpose_w3(const float* __restrict__ w1, const float* __restrict__ w2,
                             const float* __restrict__ w3, unsigned short* __restrict__ wt) {
    const int i = blockIdx.x * 256 + threadIdx.x;   // 0..49151
    const int which = i >> 14;
    const int j = i & 16383;
    const float* W = (which == 0) ? w1 : (which == 1) ? w2 : w3;
    const int n = j >> 7;
    const int k = j & 127;
    wt[i] = f2bf(W[k * F + n]);                     // Wt[n][k] = W[k][n]
}

// ---------------- MFMA bf16 GEMM, row-major, 128-row blocks ----------------
// Block 256 = 4 waves; block computes 128 rows x 128 cols. Wave w owns two
// 16-row m-tiles: rows blk*128 + w*16 (+0 / +64). K = 4 k-tiles of 32.
// W^T staged once in LDS in frag order (conflict-free ds_read_b128);
// A-frags straight from global (row-major, 16 B/lane).
__global__ __launch_bounds__(256) void gemm_mfma(
    const float* __restrict__ Xf,            // fp32 input (layer 1) or null
    const unsigned short* __restrict__ Xb,   // bf16 input (layers 2/3) or null
    const unsigned short* __restrict__ Wt,   // bf16 W^T [128][128]
    unsigned short* __restrict__ Y,          // bf16 out [N][128]
    int use_f32_in)                          // 1: Xf no relu; 0: Xb with relu
{
    __shared__ unsigned short Wl[4 * 8 * 64 * 8];   // 32 KB, frag order

    const int tid  = threadIdx.x;
    const int wave = tid >> 6;
    const int lane = tid & 63;

    for (int s = tid; s < 2048; s += 256) {
        const int ln  = s & 63;
        const int ntk = s >> 6;           // kt*8 + nt
        const int nt  = ntk & 7;
        const int kt  = ntk >> 3;
        const int n   = nt * 16 + (ln & 15);
        const int k   = kt * 32 + (ln >> 4) * 8;
        *(u32x4*)(&Wl[s * 8]) = *(const u32x4*)(Wt + n * F + k);
    }
    __syncthreads();

    const int kq = (lane >> 4) * 8;
    const int m0 = blockIdx.x * 128 + wave * 16 + (lane & 15);
    const int m1 = m0 + 64;
    const bool v0 = (m0 < N_NODES);
    const bool v1 = (m1 < N_NODES);

    f32x4 acc[2][8] = {};

#pragma unroll
    for (int kt = 0; kt < 4; ++kt) {
        ABFrag a0, a1;
        a0.q = 0;
        a1.q = 0;
        if (use_f32_in) {
            if (v0) {
                const float* p = Xf + (size_t)m0 * F + kt * 32 + kq;
                const float4 u0 = *(const float4*)p;
                const float4 u1 = *(const float4*)(p + 4);
                a0.u[0] = f2bf(u0.x); a0.u[1] = f2bf(u0.y);
                a0.u[2] = f2bf(u0.z); a0.u[3] = f2bf(u0.w);
                a0.u[4] = f2bf(u1.x); a0.u[5] = f2bf(u1.y);
                a0.u[6] = f2bf(u1.z); a0.u[7] = f2bf(u1.w);
            }
            if (v1) {
                const float* p = Xf + (size_t)m1 * F + kt * 32 + kq;
                const float4 u0 = *(const float4*)p;
                const float4 u1 = *(const float4*)(p + 4);
                a1.u[0] = f2bf(u0.x); a1.u[1] = f2bf(u0.y);
                a1.u[2] = f2bf(u0.z); a1.u[3] = f2bf(u0.w);
                a1.u[4] = f2bf(u1.x); a1.u[5] = f2bf(u1.y);
                a1.u[6] = f2bf(u1.z); a1.u[7] = f2bf(u1.w);
            }
        } else {
            if (v0) {
                a0.q = *(const u32x4*)(Xb + (size_t)m0 * F + kt * 32 + kq);
#pragma unroll
                for (int j = 0; j < 8; ++j)
                    if (a0.u[j] & 0x8000u) a0.u[j] = 0;   // relu on bf16 bits
            }
            if (v1) {
                a1.q = *(const u32x4*)(Xb + (size_t)m1 * F + kt * 32 + kq);
#pragma unroll
                for (int j = 0; j < 8; ++j)
                    if (a1.u[j] & 0x8000u) a1.u[j] = 0;
            }
        }
#pragma unroll
        for (int nt = 0; nt < 8; ++nt) {
            ABFrag b;
            b.q = *(const u32x4*)(&Wl[((kt * 8 + nt) * 64 + lane) * 8]);
            acc[0][nt] = __builtin_amdgcn_mfma_f32_16x16x32_bf16(a0.v, b.v, acc[0][nt], 0, 0, 0);
            acc[1][nt] = __builtin_amdgcn_mfma_f32_16x16x32_bf16(a1.v, b.v, acc[1][nt], 0, 0, 0);
        }
    }

    const int cbase = lane & 15;
#pragma unroll
    for (int t = 0; t < 2; ++t) {
        const int rbase = blockIdx.x * 128 + t * 64 + wave * 16 + (lane >> 4) * 4;
#pragma unroll
        for (int r = 0; r < 4; ++r) {
            const int row = rbase + r;
            if (row < N_NODES) {
#pragma unroll
                for (int nt = 0; nt < 8; ++nt) {
                    Y[(size_t)row * F + nt * 16 + cbase] = f2bf(acc[t][nt][r]);
                }
            }
        }
    }
}

// ---------------- CSR SpMM: quarter-wave per row, 4-deep unroll ----------------
// 16 lanes per row, lane covers 8 bf16 cols (16 B load, full 64 B lines per
// edge). 4 independent gathers in flight per lane. Pairs NT (streamed once);
// output stores NT so they don't evict the gather table from L2.
__global__ __launch_bounds__(256) void spmm_csr_bf16(
    const unsigned short* __restrict__ Xb,
    const int* __restrict__ row_ptr,
    const unsigned int* __restrict__ pairs,
    unsigned short* __restrict__ Ob,
    float* __restrict__ Of,
    int final_mode) {
    const int tid = threadIdx.x;
    const int l16 = tid & 15;
    const int q   = tid >> 4;
    const int row = blockIdx.x * 16 + q;

    const int beg = row_ptr[row];
    const int end = row_ptr[row + 1];

    float a[8] = {};
    int i = beg;
    for (; i + 3 < end; i += 4) {
        const unsigned int p0 = __builtin_nontemporal_load(&pairs[i]);
        const unsigned int p1 = __builtin_nontemporal_load(&pairs[i + 1]);
        const unsigned int p2 = __builtin_nontemporal_load(&pairs[i + 2]);
        const unsigned int p3 = __builtin_nontemporal_load(&pairs[i + 3]);
        const u32x4 v0 = *(const u32x4*)(Xb + (size_t)(p0 >> 15) * F + l16 * 8);
        const u32x4 v1 = *(const u32x4*)(Xb + (size_t)(p1 >> 15) * F + l16 * 8);
        const u32x4 v2 = *(const u32x4*)(Xb + (size_t)(p2 >> 15) * F + l16 * 8);
        const u32x4 v3 = *(const u32x4*)(Xb + (size_t)(p3 >> 15) * F + l16 * 8);
        const float w0 = bflo(p0 & 0x7FFFu);
        const float w1 = bflo(p1 & 0x7FFFu);
        const float w2 = bflo(p2 & 0x7FFFu);
        const float w3 = bflo(p3 & 0x7FFFu);
        a[0] += w0 * bflo(v0.x); a[1] += w0 * bfhi(v0.x);
        a[2] += w0 * bflo(v0.y); a[3] += w0 * bfhi(v0.y);
        a[4] += w0 * bflo(v0.z); a[5] += w0 * bfhi(v0.z);
        a[6] += w0 * bflo(v0.w); a[7] += w0 * bfhi(v0.w);
        a[0] += w1 * bflo(v1.x); a[1] += w1 * bfhi(v1.x);
        a[2] += w1 * bflo(v1.y); a[3] += w1 * bfhi(v1.y);
        a[4] += w1 * bflo(v1.z); a[5] += w1 * bfhi(v1.z);
        a[6] += w1 * bflo(v1.w); a[7] += w1 * bfhi(v1.w);
        a[0] += w2 * bflo(v2.x); a[1] += w2 * bfhi(v2.x);
        a[2] += w2 * bflo(v2.y); a[3] += w2 * bfhi(v2.y);
        a[4] += w2 * bflo(v2.z); a[5] += w2 * bfhi(v2.z);
        a[6] += w2 * bflo(v2.w); a[7] += w2 * bfhi(v2.w);
        a[0] += w3 * bflo(v3.x); a[1] += w3 * bfhi(v3.x);
        a[2] += w3 * bflo(v3.y); a[3] += w3 * bfhi(v3.y);
        a[4] += w3 * bflo(v3.z); a[5] += w3 * bfhi(v3.z);
        a[6] += w3 * bflo(v3.w); a[7] += w3 * bfhi(v3.w);
    }
    for (; i < end; ++i) {
        const unsigned int p0 = __builtin_nontemporal_load(&pairs[i]);
        const u32x4 v0 = *(const u32x4*)(Xb + (size_t)(p0 >> 15) * F + l16 * 8);
        const float w0 = bflo(p0 & 0x7FFFu);
        a[0] += w0 * bflo(v0.x); a[1] += w0 * bfhi(v0.x);
        a[2] += w0 * bflo(v0.y); a[3] += w0 * bfhi(v0.y);
        a[4] += w0 * bflo(v0.z); a[5] += w0 * bfhi(v0.z);
        a[6] += w0 * bflo(v0.w); a[7] += w0 * bfhi(v0.w);
    }

    if (final_mode) {
        f32x4 o0 = {fmaxf(a[0], 0.f), fmaxf(a[1], 0.f), fmaxf(a[2], 0.f), fmaxf(a[3], 0.f)};
        f32x4 o1 = {fmaxf(a[4], 0.f), fmaxf(a[5], 0.f), fmaxf(a[6], 0.f), fmaxf(a[7], 0.f)};
        float* p = Of + (size_t)row * F + l16 * 8;
        __builtin_nontemporal_store(o0, (f32x4*)p);
        __builtin_nontemporal_store(o1, (f32x4*)(p + 4));
    } else {
        u32x4 o;
        o.x = (unsigned int)f2bf(a[0]) | ((unsigned int)f2bf(a[1]) << 16);
        o.y = (unsigned int)f2bf(a[2]) | ((unsigned int)f2bf(a[3]) << 16);
        o.z = (unsigned int)f2bf(a[4]) | ((unsigned int)f2bf(a[5]) << 16);
        o.w = (unsigned int)f2bf(a[6]) | ((unsigned int)f2bf(a[7]) << 16);
        __builtin_nontemporal_store(o, (u32x4*)(Ob + (size_t)row * F + l16 * 8));
    }
}

// ---------------- launch ----------------

extern "C" void kernel_launch(void* const* d_in, const int* in_sizes, int n_in,
                              void* d_out, int out_size, void* d_ws, size_t ws_size,
                              hipStream_t stream) {
    const float* x    = (const float*)d_in[0];
    const int*   erow = (const int*)d_in[1];
    const int*   ecol = (const int*)d_in[2];
    const float* ew   = (const float*)d_in[3];
    const float* w1   = (const float*)d_in[4];
    const float* w2   = (const float*)d_in[5];
    const float* w3   = (const float*)d_in[6];
    float* out = (float*)d_out;

    char* ws = (char*)d_ws;
    size_t off = 0;
    auto alloc = [&](size_t bytes) -> char* {
        char* p = ws + off;
        off += (bytes + 255) & ~(size_t)255;
        return p;
    };
    unsigned short* bufA = (unsigned short*)alloc((size_t)N_NODES * F * 2); // 25.6 MB
    unsigned short* bufB = (unsigned short*)alloc((size_t)N_NODES * F * 2); // 25.6 MB
    unsigned int* pairs  = (unsigned int*)alloc((size_t)N_EDGES * 4);       // 6.4 MB
    int* counts  = (int*)alloc((size_t)N_NODES * sizeof(int) * 2);          // counts + cursor
    int* cursor  = counts + N_NODES;
    int* row_ptr = (int*)alloc(((size_t)N_NODES + 1) * sizeof(int));
    int* bsums   = (int*)alloc((size_t)SCAN_NB * sizeof(int));
    int* boffs   = (int*)alloc((size_t)SCAN_NB * sizeof(int));
    unsigned short* wt = (unsigned short*)alloc((size_t)3 * F * F * 2);     // wt1|wt2|wt3
    unsigned short* wt1 = wt;
    unsigned short* wt2 = wt + F * F;
    unsigned short* wt3 = wt + 2 * F * F;

    // --- CSR build (once; reused by all 3 layers) ---
    hipMemsetAsync(counts, 0, (size_t)N_NODES * sizeof(int) * 2, stream);
    edge_histogram_xcd<<<8 * (N_EDGES / 256), 256, 0, stream>>>(erow, counts);
    scan_block_sums<<<SCAN_NB, SCAN_B, 0, stream>>>(counts, bsums);
    scan_bsums<<<1, 128, 0, stream>>>(bsums, boffs);
    scan_final<<<SCAN_NB, SCAN_B, 0, stream>>>(counts, boffs, row_ptr);
    csr_fill_xcd<<<8 * (N_EDGES / 256), 256, 0, stream>>>(erow, ecol, ew, row_ptr, cursor, pairs);

    // --- Weight transposes to bf16 (one launch) ---
    transpose_w3<<<192, 256, 0, stream>>>(w1, w2, w3, wt);

    const int ggrid = (N_NODES + 127) / 128;   // 782
    const int sgrid = N_NODES / 16;            // 6250 exact

    // Layer 1
    gemm_mfma<<<ggrid, 256, 0, stream>>>(x, nullptr, wt1, bufA, 1);
    spmm_csr_bf16<<<sgrid, 256, 0, stream>>>(bufA, row_ptr, pairs, bufB, nullptr, 0);
    // Layer 2
    gemm_mfma<<<ggrid, 256, 0, stream>>>(nullptr, bufB, wt2, bufA, 0);
    spmm_csr_bf16<<<sgrid, 256, 0, stream>>>(bufA, row_ptr, pairs, bufB, nullptr, 0);
    // Layer 3
    gemm_mfma<<<ggrid, 256, 0, stream>>>(nullptr, bufB, wt3, bufA, 0);
    spmm_csr_bf16<<<sgrid, 256, 0, stream>>>(bufA, row_ptr, pairs, nullptr, out, 1);
}